// Round 8
// baseline (50.280 us; speedup 1.0000x reference)
//
#include <hip/hip_runtime.h>
#include <stdint.h>

namespace {

constexpr int Bn = 2048;
constexpr int Kn = 16;
constexpr int Mn = 131072;             // 2^17

// f32 element offsets in d_out (outputs concatenated flat in return order)
constexpr int O_NEXT   = 0;            // next_location [2048,2]
constexpr int O_SCALAR = Bn * 2;       // 4096 (scalar lp)
constexpr int O_LOC    = O_SCALAR + 1; // 4097
constexpr int O_SENS   = O_LOC + Mn * 2;  // 266241

constexpr int NCOMPB = 512;            // compute blocks FIRST (4 waves/blk, 1 row/wave)
constexpr int NCOPY  = 2048;           // copy blocks (proven R6 config)

constexpr int SENS_N = Mn * 128;       // 16777216 = 2^24 sens elements
constexpr uint32_t SMASK = SENS_N - 1;
constexpr uint32_t RMASK = Mn - 1;
constexpr uint32_t WLEN  = Bn * 128;   // 262144 window elements
// float4 groups aligned on OUTPUT: element O_SENS+e is 16B-aligned iff e%4==3.
constexpr int NG4  = 4194303;          // groups u: e = 4u+3 .. 4u+6
constexpr int TOTU = NG4 + Mn + 1;     // + loc rows + 1 edge unit (e=0,1,2,last)

typedef float f32x4   __attribute__((ext_vector_type(4)));
typedef float f32x4_u __attribute__((ext_vector_type(4), aligned(4)));  // dword-aligned 16B load

// ---------------- threefry2x32 (JAX, 20 rounds) ----------------
__device__ __forceinline__ uint32_t rotl32(uint32_t v, int d) {
  return (v << d) | (v >> (32 - d));
}
__device__ __forceinline__ void tfround(uint32_t& x0, uint32_t& x1, int r) {
  x0 += x1; x1 = rotl32(x1, r); x1 ^= x0;
}
__device__ __forceinline__ void threefry2x32(uint32_t k0, uint32_t k1,
                                             uint32_t c0, uint32_t c1,
                                             uint32_t& o0, uint32_t& o1) {
  const uint32_t ks2 = k0 ^ k1 ^ 0x1BD11BDAu;
  uint32_t x0 = c0 + k0, x1 = c1 + k1;
  tfround(x0, x1, 13); tfround(x0, x1, 15); tfround(x0, x1, 26); tfround(x0, x1, 6);
  x0 += k1;  x1 += ks2 + 1u;
  tfround(x0, x1, 17); tfround(x0, x1, 29); tfround(x0, x1, 16); tfround(x0, x1, 24);
  x0 += ks2; x1 += k0 + 2u;
  tfround(x0, x1, 13); tfround(x0, x1, 15); tfround(x0, x1, 26); tfround(x0, x1, 6);
  x0 += k0;  x1 += k1 + 3u;
  tfround(x0, x1, 17); tfround(x0, x1, 29); tfround(x0, x1, 16); tfround(x0, x1, 24);
  x0 += k1;  x1 += ks2 + 4u;
  tfround(x0, x1, 13); tfround(x0, x1, 15); tfround(x0, x1, 26); tfround(x0, x1, 6);
  o0 = x0 + ks2;
  o1 = x1 + k0 + 5u;
}

// XLA ErfInv32 (Giles polynomial)
__device__ __forceinline__ float erfinv_xla(float x) {
  float w = -log1pf(-x * x);
  float p;
  if (w < 5.0f) {
    w -= 2.5f;
    p = 2.81022636e-08f;
    p = fmaf(p, w, 3.43273939e-07f);
    p = fmaf(p, w, -3.5233877e-06f);
    p = fmaf(p, w, -4.39150654e-06f);
    p = fmaf(p, w, 0.00021858087f);
    p = fmaf(p, w, -0.00125372503f);
    p = fmaf(p, w, -0.00417768164f);
    p = fmaf(p, w, 0.246640727f);
    p = fmaf(p, w, 1.50140941f);
  } else {
    w = sqrtf(w) - 3.0f;
    p = -0.000200214257f;
    p = fmaf(p, w, 0.000100950558f);
    p = fmaf(p, w, 0.00134934322f);
    p = fmaf(p, w, -0.00367342844f);
    p = fmaf(p, w, 0.00573950773f);
    p = fmaf(p, w, -0.0076224613f);
    p = fmaf(p, w, 0.00943887047f);
    p = fmaf(p, w, 1.00167406f);
    p = fmaf(p, w, 2.83297682f);
  }
  return p * x;
}
__device__ __forceinline__ float bits_to_normal(uint32_t bits) {
  const float lo = __int_as_float(0xBF7FFFFF);        // nextafter(-1,0) f32
  float f = __uint_as_float((bits >> 9) | 0x3F800000u) - 1.0f;
  float u = fmaxf(lo, f * 2.0f + lo);                 // (hi-lo) rounds to 2.0f
  return 1.41421356237f * erfinv_xla(u);
}
// partitionable threefry: element i <- counter (0, i), output = bits1 ^ bits2
__device__ __forceinline__ float noise_part(uint32_t key_lo, uint32_t i) {
  uint32_t o0, o1;
  threefry2x32(0u, key_lo, 0u, i, o0, o1);
  return bits_to_normal(o0 ^ o1);
}

__device__ __forceinline__ float wave_sum(float v) {
#pragma unroll
  for (int off = 32; off > 0; off >>= 1) v += __shfl_xor(v, off);
  return v;
}

// Wave-parallel localizer: lane owns hidden units 4*lane..4*lane+3.
__device__ __forceinline__ void localizer_wave(
    int lane,
    float x0, float x1, float x2, float x3, float x4, float x5,
    const float* __restrict__ W1, const float* __restrict__ b1,
    const float* __restrict__ W2, const float* __restrict__ b2,
    const float* __restrict__ V1, const float* __restrict__ c1,
    const float* __restrict__ V2, const float* __restrict__ c2,
    float vs_exp,
    float& m0, float& m1, float& sd0, float& sd1) {
  const int h = lane << 2;
  const float4 bb = *(const float4*)(b1 + h);
  const float4 w0 = *(const float4*)(W1 + h);
  const float4 w1 = *(const float4*)(W1 + 256 + h);
  const float4 w2 = *(const float4*)(W1 + 512 + h);
  const float4 w3 = *(const float4*)(W1 + 768 + h);
  const float4 w4 = *(const float4*)(W1 + 1024 + h);
  const float4 w5 = *(const float4*)(W1 + 1280 + h);
  float t0 = bb.x, t1 = bb.y, t2 = bb.z, t3 = bb.w;
  t0 = fmaf(x0, w0.x, t0); t1 = fmaf(x0, w0.y, t1); t2 = fmaf(x0, w0.z, t2); t3 = fmaf(x0, w0.w, t3);
  t0 = fmaf(x1, w1.x, t0); t1 = fmaf(x1, w1.y, t1); t2 = fmaf(x1, w1.z, t2); t3 = fmaf(x1, w1.w, t3);
  t0 = fmaf(x2, w2.x, t0); t1 = fmaf(x2, w2.y, t1); t2 = fmaf(x2, w2.z, t2); t3 = fmaf(x2, w2.w, t3);
  t0 = fmaf(x3, w3.x, t0); t1 = fmaf(x3, w3.y, t1); t2 = fmaf(x3, w3.z, t2); t3 = fmaf(x3, w3.w, t3);
  t0 = fmaf(x4, w4.x, t0); t1 = fmaf(x4, w4.y, t1); t2 = fmaf(x4, w4.z, t2); t3 = fmaf(x4, w4.w, t3);
  t0 = fmaf(x5, w5.x, t0); t1 = fmaf(x5, w5.y, t1); t2 = fmaf(x5, w5.z, t2); t3 = fmaf(x5, w5.w, t3);
  t0 = fmaxf(t0, 0.f); t1 = fmaxf(t1, 0.f); t2 = fmaxf(t2, 0.f); t3 = fmaxf(t3, 0.f);
  const float4 u0 = *(const float4*)(W2 + 2 * h);
  const float4 u1 = *(const float4*)(W2 + 2 * h + 4);
  float pa0 = t0 * u0.x; float pa1 = t0 * u0.y;
  pa0 = fmaf(t1, u0.z, pa0); pa1 = fmaf(t1, u0.w, pa1);
  pa0 = fmaf(t2, u1.x, pa0); pa1 = fmaf(t2, u1.y, pa1);
  pa0 = fmaf(t3, u1.z, pa0); pa1 = fmaf(t3, u1.w, pa1);
  m0 = wave_sum(pa0) + b2[0];
  m1 = wave_sum(pa1) + b2[1];

  const float4 cc = *(const float4*)(c1 + h);
  const float4 v0 = *(const float4*)(V1 + h);
  const float4 v1 = *(const float4*)(V1 + 256 + h);
  float s0 = cc.x, s1 = cc.y, s2 = cc.z, s3 = cc.w;
  s0 = fmaf(m0, v0.x, s0); s1 = fmaf(m0, v0.y, s1); s2 = fmaf(m0, v0.z, s2); s3 = fmaf(m0, v0.w, s3);
  s0 = fmaf(m1, v1.x, s0); s1 = fmaf(m1, v1.y, s1); s2 = fmaf(m1, v1.z, s2); s3 = fmaf(m1, v1.w, s3);
  s0 = fmaxf(s0, 0.f); s1 = fmaxf(s1, 0.f); s2 = fmaxf(s2, 0.f); s3 = fmaxf(s3, 0.f);
  const float4 q0 = *(const float4*)(V2 + 2 * h);
  const float4 q1 = *(const float4*)(V2 + 2 * h + 4);
  float ps0 = s0 * q0.x; float ps1 = s0 * q0.y;
  ps0 = fmaf(s1, q0.z, ps0); ps1 = fmaf(s1, q0.w, ps1);
  ps0 = fmaf(s2, q1.x, ps0); ps1 = fmaf(s2, q1.y, ps1);
  ps0 = fmaf(s3, q1.z, ps0); ps1 = fmaf(s3, q1.w, ps1);
  const float sv0 = wave_sum(ps0) + c2[0];
  const float sv1 = wave_sum(ps1) + c2[1];
  sd0 = fmaf(vs_exp, expf(sv0), 1e-6f);
  sd1 = fmaf(vs_exp, expf(sv1), 1e-6f);
}

__global__ __launch_bounds__(256) void fused_kernel(
    const float* __restrict__ sensory, const float* __restrict__ last_location,
    const float* __restrict__ action, const float* __restrict__ heading,
    const float* __restrict__ mem_locations, const float* __restrict__ mem_sensory,
    const float* __restrict__ W1, const float* __restrict__ b1,
    const float* __restrict__ W2, const float* __restrict__ b2,
    const float* __restrict__ V1, const float* __restrict__ c1,
    const float* __restrict__ V2, const float* __restrict__ c2,
    const float* __restrict__ vs_logits,
    const int* __restrict__ mvc_p, const int* __restrict__ wp_p,
    float* __restrict__ out, float* __restrict__ ws,
    unsigned* __restrict__ counter) {
  __shared__ float redc[4][4];
  __shared__ bool amLast;

  const int mvc = *mvc_p;
  const uint32_t wpm = (uint32_t)(*wp_p) & RMASK;   // write_ptr mod 2^17
  const uint32_t wlo = wpm << 7;                    // window start element

  if (blockIdx.x >= NCOMPB) {
    // ---------------- streaming copy path (f32 -> f32), R6-proven ----------
    // unit u < NG4: output group e = 4u+3..4u+6 (store 16B-aligned).
    //   ONE dword-aligned 16B load, single modular window-overlap test,
    //   rare per-element fixups (~1.6% of groups). NONTEMPORAL store:
    //   use-once write stream must bypass L2/LLC allocation (R7 regression
    //   proved regular stores halve effective BW here).
    const int stride = NCOPY * 256;
    for (int u = (int)(blockIdx.x - NCOMPB) * 256 + (int)threadIdx.x;
         u < TOTU; u += stride) {
      if (u < NG4) {
        const int e0 = 4 * u + 3;
        f32x4 q = *(const f32x4_u*)(mem_sensory + e0);
        const uint32_t d = ((uint32_t)(e0 + 3) - wlo) & SMASK;
        if (d < WLEN + 3) {                    // group overlaps scatter window
#pragma unroll
          for (int t = 0; t < 4; ++t) {
            const uint32_t e = (uint32_t)(e0 + t);
            const uint32_t bb = ((e >> 7) - wpm) & RMASK;
            if (bb < Bn) q[t] = sensory[(bb << 7) | (e & 127u)];
          }
        }
        __builtin_nontemporal_store(q, (f32x4*)(out + O_SENS + e0));
      } else if (u < NG4 + Mn) {
        const uint32_t r = (uint32_t)(u - NG4);
        const uint32_t bb = (r - wpm) & RMASK;
        if (bb >= Bn) {
          const float2 v = *(const float2*)(mem_locations + 2 * r);
          out[O_LOC + 2 * r]     = v.x;
          out[O_LOC + 2 * r + 1] = v.y;
        }
      } else {
        const uint32_t bb0 = (0u - wpm) & RMASK;
#pragma unroll
        for (int t = 0; t < 3; ++t)            // e = 0, 1, 2 (row 0)
          out[O_SENS + t] = (bb0 < Bn) ? sensory[(bb0 << 7) | t] : mem_sensory[t];
        {  // e = SENS_N - 1 (row Mn-1)
          const int e = SENS_N - 1;
          const uint32_t bb = ((uint32_t)(Mn - 1) - wpm) & RMASK;
          out[O_SENS + e] = (bb < Bn) ? sensory[(bb << 7) | 127] : mem_sensory[e];
        }
      }
    }
  } else {
    // ---------------- compute path: 1 row per wave (blocks 0..511 first) ----
    const int cb = blockIdx.x;
    const int wid = threadIdx.x >> 6;
    const int lane = threadIdx.x & 63;
    const int b = cb * 4 + wid;                   // row 0..2047

    // noise: 4 values lane-split then broadcast
    const uint32_t nk = 1u + ((lane >> 1) & 1u);  // lanes {0,1}->key1, {2,3}->key2
    const uint32_t ni = (uint32_t)(2 * b) + (lane & 1u);
    const float nv = noise_part(nk, ni);
    const float n1a = __shfl(nv, 0);
    const float n1b = __shfl(nv, 1);
    const float n2a = __shfl(nv, 2);
    const float n2b = __shfl(nv, 3);

    const float vs_exp = expf(vs_logits[0]);
    const float l0 = last_location[2 * b], l1 = last_location[2 * b + 1];
    const float a0 = action[4 * b],     a1 = action[4 * b + 1];
    const float a2 = action[4 * b + 2], a3 = action[4 * b + 3];
    const float h0 = heading[4 * b],     h1 = heading[4 * b + 1];
    const float h2 = heading[4 * b + 2], h3 = heading[4 * b + 3];

    // stage 1
    float m10, m11, sd10, sd11;
    localizer_wave(lane, l0, l1, a0, a1, a2, a3, W1, b1, W2, b2, V1, c1, V2, c2,
                   vs_exp, m10, m11, sd10, sd11);
    const float nl0 = m10 + n1a * sd10;
    const float nl1 = m11 + n1b * sd11;
    if (lane == 0) *(float2*)(out + 2 * b) = make_float2(nl0, nl1);

    const float d0 = (nl0 - m10) / sd10;
    const float d1 = (nl1 - m11) / sd11;
    const float v_sq1 = d0 * d0 + d1 * d1;
    const float v_lg1 = logf(sd10) + logf(sd11);

    // stage 2
    float m20, m21, sd20, sd21;
    localizer_wave(lane, nl0, nl1, h0, h1, h2, h3, W1, b1, W2, b2, V1, c1, V2, c2,
                   vs_exp, m20, m21, sd20, sd21);

    // select_location: inverted mask keeps matches at k >= found;
    // guess k = mem_locations[k] (stable top_k over all-(-inf) invalid tail)
    const int found = (mvc < Kn) ? mvc : Kn;
    const bool ignore = (found == 0);
    const float NEG_INF = -__builtin_huge_valf();

    const float qn = sqrtf(m20 * m20 + m21 * m21);
    const float q0 = m20 / qn, q1 = m21 / qn;

    float mk[Kn];
#pragma unroll
    for (int k = 0; k < Kn; ++k) {
      if (k >= found) {
        const float g0 = mem_locations[2 * k], g1 = mem_locations[2 * k + 1];
        const float gn = sqrtf(g0 * g0 + g1 * g1);
        mk[k] = (g0 / gn) * q0 + (g1 / gn) * q1;
      } else {
        mk[k] = NEG_INF;
      }
    }
    float mmax = NEG_INF;
#pragma unroll
    for (int k = 0; k < Kn; ++k) mmax = fmaxf(mmax, mk[k]);
    float wsum = 0.f;
#pragma unroll
    for (int k = 0; k < Kn; ++k) {
      mk[k] = expf(mk[k] - mmax);   // exp(-inf - finite) = 0
      wsum += mk[k];
    }
    float i0 = 0.f, i1 = 0.f;
#pragma unroll
    for (int k = 0; k < Kn; ++k) {
      const float wn = mk[k] / wsum;
      i0 = fmaf(wn, mem_locations[2 * k], i0);
      i1 = fmaf(wn, mem_locations[2 * k + 1], i1);
    }

    const float z0 = (i0 - m20) / sd20, z1 = (i1 - m21) / sd21;
    const float hz0 = -0.5f * z0, hz1 = -0.5f * z1;
    const bool too_far = sqrtf(hz0 * hz0 + hz1 * hz1) > 2.0f;  // NaN -> false
    const float e0 = m20 + n2a * sd20;
    const float e1 = m20 == m20 ? m21 + n2b * sd21 : 0.f;      // keep simple: e1 below
    const float e1v = m21 + n2b * sd21;
    const bool c0 = too_far || ignore || __builtin_isnan(i0);
    const bool c1 = too_far || ignore || __builtin_isnan(i1);
    const float o0 = c0 ? i0 : e0;
    const float o1 = c1 ? i1 : e1v;
    (void)e1;

    if (lane == 0) {
      const uint32_t row = (wpm + (uint32_t)b) & RMASK;
      out[O_LOC + 2 * row]     = o0;
      out[O_LOC + 2 * row + 1] = o1;
    }

    const float zo0 = (o0 - m20) / sd20, zo1 = (o1 - m21) / sd21;
    const float v_sq2 = zo0 * zo0 + zo1 * zo1;
    const float v_lg2 = logf(sd20) + logf(sd21);

    if (lane == 0) {
      redc[wid][0] = v_sq1; redc[wid][1] = v_lg1;
      redc[wid][2] = v_sq2; redc[wid][3] = v_lg2;
    }
    __syncthreads();
    if (threadIdx.x == 0) {
      float s0 = 0.f, s1 = 0.f, s2 = 0.f, s3 = 0.f;
#pragma unroll
      for (int w = 0; w < 4; ++w) {
        s0 += redc[w][0]; s1 += redc[w][1]; s2 += redc[w][2]; s3 += redc[w][3];
      }
      ws[4 * cb + 0] = s0; ws[4 * cb + 1] = s1;
      ws[4 * cb + 2] = s2; ws[4 * cb + 3] = s3;
      __threadfence();                            // release partials
      const unsigned old = atomicAdd(counter, 1u);
      amLast = (old == (unsigned)(NCOMPB - 1));
    }
    __syncthreads();
    // last compute block folds the 512 partials while copy blocks still run
    // (off the critical path); fixed-order sums -> deterministic
    if (amLast && threadIdx.x < 64) {
      __threadfence();                            // acquire partials
      const int lane64 = threadIdx.x;
      float s0 = 0.f, s1 = 0.f, s2 = 0.f, s3 = 0.f;
      for (int i = lane64; i < NCOMPB; i += 64) {
        s0 += ws[4 * i + 0]; s1 += ws[4 * i + 1];
        s2 += ws[4 * i + 2]; s3 += ws[4 * i + 3];
      }
#pragma unroll
      for (int off = 32; off > 0; off >>= 1) {
        s0 += __shfl_xor(s0, off); s1 += __shfl_xor(s1, off);
        s2 += __shfl_xor(s2, off); s3 += __shfl_xor(s3, off);
      }
      if (lane64 == 0) {
        const float invB = 1.0f / (float)Bn;
        const float nl_lp  = -0.5f * (s0 * invB) - (s1 * invB);
        const float obj_lp = -0.5f * (s2 * invB) - (s3 * invB);
        out[O_SCALAR] = nl_lp + obj_lp;
      }
    }
  }
}

}  // namespace

extern "C" void kernel_launch(void* const* d_in, const int* in_sizes, int n_in,
                              void* d_out, int out_size, void* d_ws, size_t ws_size,
                              hipStream_t stream) {
  const float* sensory       = (const float*)d_in[0];
  const float* last_location = (const float*)d_in[1];
  const float* action        = (const float*)d_in[2];
  const float* heading       = (const float*)d_in[3];
  const float* mem_locations = (const float*)d_in[4];
  const float* mem_sensory   = (const float*)d_in[5];
  const float* W1 = (const float*)d_in[6];
  const float* b1 = (const float*)d_in[7];
  const float* W2 = (const float*)d_in[8];
  const float* b2 = (const float*)d_in[9];
  const float* V1 = (const float*)d_in[10];
  const float* c1 = (const float*)d_in[11];
  const float* V2 = (const float*)d_in[12];
  const float* c2 = (const float*)d_in[13];
  const float* vs = (const float*)d_in[14];
  const int* mvc  = (const int*)d_in[15];
  const int* wp   = (const int*)d_in[16];
  float* out = (float*)d_out;
  float* ws  = (float*)d_ws;
  // counter lives past the 512*4 float partials (8 KB) in d_ws
  unsigned* counter = (unsigned*)((char*)d_ws + 8192);

  hipMemsetAsync(counter, 0, sizeof(unsigned), stream);  // graph-capturable node
  fused_kernel<<<dim3(NCOMPB + NCOPY), dim3(256), 0, stream>>>(
      sensory, last_location, action, heading, mem_locations, mem_sensory,
      W1, b1, W2, b2, V1, c1, V2, c2, vs, mvc, wp, out, ws, counter);
}

// Round 9
// 33.375 us; speedup vs baseline: 1.5066x; 1.5066x over previous
//
#include <hip/hip_runtime.h>
#include <stdint.h>

namespace {

constexpr int Bn = 2048;
constexpr int Kn = 16;
constexpr int Mn = 131072;             // 2^17

// f32 element offsets in d_out (outputs concatenated flat in return order)
constexpr int O_NEXT   = 0;            // next_location [2048,2]
constexpr int O_SCALAR = Bn * 2;       // 4096 (scalar lp)
constexpr int O_LOC    = O_SCALAR + 1; // 4097
constexpr int O_SENS   = O_LOC + Mn * 2;  // 266241

constexpr int NCOMPB = 512;            // compute blocks FIRST (4 waves/blk, 1 row/wave)
constexpr int NCOPY  = 2048;           // copy blocks
constexpr int GPB    = 2048;           // groups per copy block (contiguous)
constexpr int NTILE  = GPB / 256;      // 8 LDS-staged tiles per block

constexpr int SENS_N = Mn * 128;       // 16777216 = 2^24 sens elements
constexpr uint32_t SMASK = SENS_N - 1;
constexpr uint32_t RMASK = Mn - 1;
constexpr uint32_t WLEN  = Bn * 128;   // 262144 window elements
// float4 groups aligned on OUTPUT: element O_SENS+e is 16B-aligned iff e%4==3.
constexpr int NG4 = 4194303;           // groups g: e = 4g+3 .. 4g+6 (e max 16777214)
constexpr int LOC_PER_BLK = Mn / NCOPY;  // 64 loc rows per copy block

typedef float f32x4 __attribute__((ext_vector_type(4)));

// ---------------- threefry2x32 (JAX, 20 rounds) ----------------
__device__ __forceinline__ uint32_t rotl32(uint32_t v, int d) {
  return (v << d) | (v >> (32 - d));
}
__device__ __forceinline__ void tfround(uint32_t& x0, uint32_t& x1, int r) {
  x0 += x1; x1 = rotl32(x1, r); x1 ^= x0;
}
__device__ __forceinline__ void threefry2x32(uint32_t k0, uint32_t k1,
                                             uint32_t c0, uint32_t c1,
                                             uint32_t& o0, uint32_t& o1) {
  const uint32_t ks2 = k0 ^ k1 ^ 0x1BD11BDAu;
  uint32_t x0 = c0 + k0, x1 = c1 + k1;
  tfround(x0, x1, 13); tfround(x0, x1, 15); tfround(x0, x1, 26); tfround(x0, x1, 6);
  x0 += k1;  x1 += ks2 + 1u;
  tfround(x0, x1, 17); tfround(x0, x1, 29); tfround(x0, x1, 16); tfround(x0, x1, 24);
  x0 += ks2; x1 += k0 + 2u;
  tfround(x0, x1, 13); tfround(x0, x1, 15); tfround(x0, x1, 26); tfround(x0, x1, 6);
  x0 += k0;  x1 += k1 + 3u;
  tfround(x0, x1, 17); tfround(x0, x1, 29); tfround(x0, x1, 16); tfround(x0, x1, 24);
  x0 += k1;  x1 += ks2 + 4u;
  tfround(x0, x1, 13); tfround(x0, x1, 15); tfround(x0, x1, 26); tfround(x0, x1, 6);
  o0 = x0 + ks2;
  o1 = x1 + k0 + 5u;
}

// XLA ErfInv32 (Giles polynomial)
__device__ __forceinline__ float erfinv_xla(float x) {
  float w = -log1pf(-x * x);
  float p;
  if (w < 5.0f) {
    w -= 2.5f;
    p = 2.81022636e-08f;
    p = fmaf(p, w, 3.43273939e-07f);
    p = fmaf(p, w, -3.5233877e-06f);
    p = fmaf(p, w, -4.39150654e-06f);
    p = fmaf(p, w, 0.00021858087f);
    p = fmaf(p, w, -0.00125372503f);
    p = fmaf(p, w, -0.00417768164f);
    p = fmaf(p, w, 0.246640727f);
    p = fmaf(p, w, 1.50140941f);
  } else {
    w = sqrtf(w) - 3.0f;
    p = -0.000200214257f;
    p = fmaf(p, w, 0.000100950558f);
    p = fmaf(p, w, 0.00134934322f);
    p = fmaf(p, w, -0.00367342844f);
    p = fmaf(p, w, 0.00573950773f);
    p = fmaf(p, w, -0.0076224613f);
    p = fmaf(p, w, 0.00943887047f);
    p = fmaf(p, w, 1.00167406f);
    p = fmaf(p, w, 2.83297682f);
  }
  return p * x;
}
__device__ __forceinline__ float bits_to_normal(uint32_t bits) {
  const float lo = __int_as_float(0xBF7FFFFF);        // nextafter(-1,0) f32
  float f = __uint_as_float((bits >> 9) | 0x3F800000u) - 1.0f;
  float u = fmaxf(lo, f * 2.0f + lo);                 // (hi-lo) rounds to 2.0f
  return 1.41421356237f * erfinv_xla(u);
}
// partitionable threefry: element i <- counter (0, i), output = bits1 ^ bits2
__device__ __forceinline__ float noise_part(uint32_t key_lo, uint32_t i) {
  uint32_t o0, o1;
  threefry2x32(0u, key_lo, 0u, i, o0, o1);
  return bits_to_normal(o0 ^ o1);
}

__device__ __forceinline__ float wave_sum(float v) {
#pragma unroll
  for (int off = 32; off > 0; off >>= 1) v += __shfl_xor(v, off);
  return v;
}

// Wave-parallel localizer: lane owns hidden units 4*lane..4*lane+3.
__device__ __forceinline__ void localizer_wave(
    int lane,
    float x0, float x1, float x2, float x3, float x4, float x5,
    const float* __restrict__ W1, const float* __restrict__ b1,
    const float* __restrict__ W2, const float* __restrict__ b2,
    const float* __restrict__ V1, const float* __restrict__ c1,
    const float* __restrict__ V2, const float* __restrict__ c2,
    float vs_exp,
    float& m0, float& m1, float& sd0, float& sd1) {
  const int h = lane << 2;
  const float4 bb = *(const float4*)(b1 + h);
  const float4 w0 = *(const float4*)(W1 + h);
  const float4 w1 = *(const float4*)(W1 + 256 + h);
  const float4 w2 = *(const float4*)(W1 + 512 + h);
  const float4 w3 = *(const float4*)(W1 + 768 + h);
  const float4 w4 = *(const float4*)(W1 + 1024 + h);
  const float4 w5 = *(const float4*)(W1 + 1280 + h);
  float t0 = bb.x, t1 = bb.y, t2 = bb.z, t3 = bb.w;
  t0 = fmaf(x0, w0.x, t0); t1 = fmaf(x0, w0.y, t1); t2 = fmaf(x0, w0.z, t2); t3 = fmaf(x0, w0.w, t3);
  t0 = fmaf(x1, w1.x, t0); t1 = fmaf(x1, w1.y, t1); t2 = fmaf(x1, w1.z, t2); t3 = fmaf(x1, w1.w, t3);
  t0 = fmaf(x2, w2.x, t0); t1 = fmaf(x2, w2.y, t1); t2 = fmaf(x2, w2.z, t2); t3 = fmaf(x2, w2.w, t3);
  t0 = fmaf(x3, w3.x, t0); t1 = fmaf(x3, w3.y, t1); t2 = fmaf(x3, w3.z, t2); t3 = fmaf(x3, w3.w, t3);
  t0 = fmaf(x4, w4.x, t0); t1 = fmaf(x4, w4.y, t1); t2 = fmaf(x4, w4.z, t2); t3 = fmaf(x4, w4.w, t3);
  t0 = fmaf(x5, w5.x, t0); t1 = fmaf(x5, w5.y, t1); t2 = fmaf(x5, w5.z, t2); t3 = fmaf(x5, w5.w, t3);
  t0 = fmaxf(t0, 0.f); t1 = fmaxf(t1, 0.f); t2 = fmaxf(t2, 0.f); t3 = fmaxf(t3, 0.f);
  const float4 u0 = *(const float4*)(W2 + 2 * h);
  const float4 u1 = *(const float4*)(W2 + 2 * h + 4);
  float pa0 = t0 * u0.x; float pa1 = t0 * u0.y;
  pa0 = fmaf(t1, u0.z, pa0); pa1 = fmaf(t1, u0.w, pa1);
  pa0 = fmaf(t2, u1.x, pa0); pa1 = fmaf(t2, u1.y, pa1);
  pa0 = fmaf(t3, u1.z, pa0); pa1 = fmaf(t3, u1.w, pa1);
  m0 = wave_sum(pa0) + b2[0];
  m1 = wave_sum(pa1) + b2[1];

  const float4 cc = *(const float4*)(c1 + h);
  const float4 v0 = *(const float4*)(V1 + h);
  const float4 v1 = *(const float4*)(V1 + 256 + h);
  float s0 = cc.x, s1 = cc.y, s2 = cc.z, s3 = cc.w;
  s0 = fmaf(m0, v0.x, s0); s1 = fmaf(m0, v0.y, s1); s2 = fmaf(m0, v0.z, s2); s3 = fmaf(m0, v0.w, s3);
  s0 = fmaf(m1, v1.x, s0); s1 = fmaf(m1, v1.y, s1); s2 = fmaf(m1, v1.z, s2); s3 = fmaf(m1, v1.w, s3);
  s0 = fmaxf(s0, 0.f); s1 = fmaxf(s1, 0.f); s2 = fmaxf(s2, 0.f); s3 = fmaxf(s3, 0.f);
  const float4 q0 = *(const float4*)(V2 + 2 * h);
  const float4 q1 = *(const float4*)(V2 + 2 * h + 4);
  float ps0 = s0 * q0.x; float ps1 = s0 * q0.y;
  ps0 = fmaf(s1, q0.z, ps0); ps1 = fmaf(s1, q0.w, ps1);
  ps0 = fmaf(s2, q1.x, ps0); ps1 = fmaf(s2, q1.y, ps1);
  ps0 = fmaf(s3, q1.z, ps0); ps1 = fmaf(s3, q1.w, ps1);
  const float sv0 = wave_sum(ps0) + c2[0];
  const float sv1 = wave_sum(ps1) + c2[1];
  sd0 = fmaf(vs_exp, expf(sv0), 1e-6f);
  sd1 = fmaf(vs_exp, expf(sv1), 1e-6f);
}

__global__ __launch_bounds__(256) void fused_kernel(
    const float* __restrict__ sensory, const float* __restrict__ last_location,
    const float* __restrict__ action, const float* __restrict__ heading,
    const float* __restrict__ mem_locations, const float* __restrict__ mem_sensory,
    const float* __restrict__ W1, const float* __restrict__ b1,
    const float* __restrict__ W2, const float* __restrict__ b2,
    const float* __restrict__ V1, const float* __restrict__ c1,
    const float* __restrict__ V2, const float* __restrict__ c2,
    const float* __restrict__ vs_logits,
    const int* __restrict__ mvc_p, const int* __restrict__ wp_p,
    float* __restrict__ out, float* __restrict__ ws) {
  const int mvc = *mvc_p;
  const uint32_t wpm = (uint32_t)(*wp_p) & RMASK;   // write_ptr mod 2^17
  const uint32_t wlo = wpm << 7;                    // window start element

  if (blockIdx.x >= NCOMPB) {
    // ------------- streaming copy path: LDS-staged, fully aligned -----------
    // Block owns GPB contiguous groups. Per tile of 256 groups: stage the
    // 1028-float aligned input window in LDS (257 aligned float4 loads),
    // then each thread reads its +3-shifted 4 floats from LDS, applies the
    // rare scatter-window fixup, and nt-stores one aligned float4.
    __shared__ f32x4 buf[2][257];
    const int cb = blockIdx.x - NCOMPB;
    const int tid = threadIdx.x;
    int p = 0;
#pragma unroll
    for (int tile = 0; tile < NTILE; ++tile) {
      const int gbase = cb * GPB + tile * 256;   // first group of tile
      const int abase = 4 * gbase;               // aligned float base (window = abase..abase+1028)
      buf[p][tid] = *(const f32x4*)(mem_sensory + abase + 4 * tid);
      if (tid == 0 && abase + 1028 <= SENS_N)
        buf[p][256] = *(const f32x4*)(mem_sensory + abase + 1024);
      __syncthreads();
      const int g = gbase + tid;
      if (g < NG4) {
        const float* lf = (const float*)&buf[p][0];
        const int off = 4 * tid + 3;
        f32x4 q = {lf[off], lf[off + 1], lf[off + 2], lf[off + 3]};
        const int e0 = 4 * g + 3;
        const uint32_t d = ((uint32_t)(e0 + 3) - wlo) & SMASK;
        if (d < WLEN + 3) {                      // group overlaps scatter window
#pragma unroll
          for (int t = 0; t < 4; ++t) {
            const uint32_t e = (uint32_t)(e0 + t);
            const uint32_t bb = ((e >> 7) - wpm) & RMASK;
            if (bb < Bn) q[t] = sensory[(bb << 7) | (e & 127u)];
          }
        }
        __builtin_nontemporal_store(q, (f32x4*)(out + O_SENS + e0));
      }
      p ^= 1;
    }
    // loc rows: 64 contiguous rows per block, skipped if in scatter window
    if (tid < LOC_PER_BLK) {
      const uint32_t r = (uint32_t)(cb * LOC_PER_BLK + tid);
      const uint32_t bb = (r - wpm) & RMASK;
      if (bb >= Bn) {
        const float2 v = *(const float2*)(mem_locations + 2 * r);
        __builtin_nontemporal_store(v.x, out + O_LOC + 2 * r);
        __builtin_nontemporal_store(v.y, out + O_LOC + 2 * r + 1);
      }
    }
    // edge sens elements e = 0,1,2 and SENS_N-1 (block 0, thread 64)
    if (cb == 0 && tid == 64) {
      const uint32_t bb0 = (0u - wpm) & RMASK;
#pragma unroll
      for (int t = 0; t < 3; ++t)
        out[O_SENS + t] = (bb0 < Bn) ? sensory[(bb0 << 7) | t] : mem_sensory[t];
      const int e = SENS_N - 1;
      const uint32_t bbl = ((uint32_t)(Mn - 1) - wpm) & RMASK;
      out[O_SENS + e] = (bbl < Bn) ? sensory[(bbl << 7) | 127] : mem_sensory[e];
    }
  } else {
    // ---------------- compute path: 1 row per wave (blocks 0..511 first) ----
    __shared__ float redc[4][4];
    const int cb = blockIdx.x;
    const int wid = threadIdx.x >> 6;
    const int lane = threadIdx.x & 63;
    const int b = cb * 4 + wid;                   // row 0..2047

    // noise: 4 values lane-split then broadcast
    const uint32_t nk = 1u + ((lane >> 1) & 1u);  // lanes {0,1}->key1, {2,3}->key2
    const uint32_t ni = (uint32_t)(2 * b) + (lane & 1u);
    const float nv = noise_part(nk, ni);
    const float n1a = __shfl(nv, 0);
    const float n1b = __shfl(nv, 1);
    const float n2a = __shfl(nv, 2);
    const float n2b = __shfl(nv, 3);

    const float vs_exp = expf(vs_logits[0]);
    const float l0 = last_location[2 * b], l1 = last_location[2 * b + 1];
    const float a0 = action[4 * b],     a1 = action[4 * b + 1];
    const float a2 = action[4 * b + 2], a3 = action[4 * b + 3];
    const float h0 = heading[4 * b],     h1 = heading[4 * b + 1];
    const float h2 = heading[4 * b + 2], h3 = heading[4 * b + 3];

    // stage 1
    float m10, m11, sd10, sd11;
    localizer_wave(lane, l0, l1, a0, a1, a2, a3, W1, b1, W2, b2, V1, c1, V2, c2,
                   vs_exp, m10, m11, sd10, sd11);
    const float nl0 = m10 + n1a * sd10;
    const float nl1 = m11 + n1b * sd11;
    if (lane == 0) *(float2*)(out + 2 * b) = make_float2(nl0, nl1);

    const float d0 = (nl0 - m10) / sd10;
    const float d1 = (nl1 - m11) / sd11;
    const float v_sq1 = d0 * d0 + d1 * d1;
    const float v_lg1 = logf(sd10) + logf(sd11);

    // stage 2
    float m20, m21, sd20, sd21;
    localizer_wave(lane, nl0, nl1, h0, h1, h2, h3, W1, b1, W2, b2, V1, c1, V2, c2,
                   vs_exp, m20, m21, sd20, sd21);

    // select_location: inverted mask keeps matches at k >= found;
    // guess k = mem_locations[k] (stable top_k over all-(-inf) invalid tail)
    const int found = (mvc < Kn) ? mvc : Kn;
    const bool ignore = (found == 0);
    const float NEG_INF = -__builtin_huge_valf();

    const float qn = sqrtf(m20 * m20 + m21 * m21);
    const float q0 = m20 / qn, q1 = m21 / qn;

    float mk[Kn];
#pragma unroll
    for (int k = 0; k < Kn; ++k) {
      if (k >= found) {
        const float g0 = mem_locations[2 * k], g1 = mem_locations[2 * k + 1];
        const float gn = sqrtf(g0 * g0 + g1 * g1);
        mk[k] = (g0 / gn) * q0 + (g1 / gn) * q1;
      } else {
        mk[k] = NEG_INF;
      }
    }
    float mmax = NEG_INF;
#pragma unroll
    for (int k = 0; k < Kn; ++k) mmax = fmaxf(mmax, mk[k]);
    float wsum = 0.f;
#pragma unroll
    for (int k = 0; k < Kn; ++k) {
      mk[k] = expf(mk[k] - mmax);   // exp(-inf - finite) = 0
      wsum += mk[k];
    }
    float i0 = 0.f, i1 = 0.f;
#pragma unroll
    for (int k = 0; k < Kn; ++k) {
      const float wn = mk[k] / wsum;
      i0 = fmaf(wn, mem_locations[2 * k], i0);
      i1 = fmaf(wn, mem_locations[2 * k + 1], i1);
    }

    const float z0 = (i0 - m20) / sd20, z1 = (i1 - m21) / sd21;
    const float hz0 = -0.5f * z0, hz1 = -0.5f * z1;
    const bool too_far = sqrtf(hz0 * hz0 + hz1 * hz1) > 2.0f;  // NaN -> false
    const float e0 = m20 + n2a * sd20;
    const float e1 = m21 + n2b * sd21;
    const bool c0 = too_far || ignore || __builtin_isnan(i0);
    const bool c1 = too_far || ignore || __builtin_isnan(i1);
    const float o0 = c0 ? i0 : e0;
    const float o1 = c1 ? i1 : e1;

    if (lane == 0) {
      const uint32_t row = (wpm + (uint32_t)b) & RMASK;
      out[O_LOC + 2 * row]     = o0;
      out[O_LOC + 2 * row + 1] = o1;
    }

    const float zo0 = (o0 - m20) / sd20, zo1 = (o1 - m21) / sd21;
    const float v_sq2 = zo0 * zo0 + zo1 * zo1;
    const float v_lg2 = logf(sd20) + logf(sd21);

    if (lane == 0) {
      redc[wid][0] = v_sq1; redc[wid][1] = v_lg1;
      redc[wid][2] = v_sq2; redc[wid][3] = v_lg2;
    }
    __syncthreads();
    if (threadIdx.x == 0) {
      float s0 = 0.f, s1 = 0.f, s2 = 0.f, s3 = 0.f;
#pragma unroll
      for (int w = 0; w < 4; ++w) {
        s0 += redc[w][0]; s1 += redc[w][1]; s2 += redc[w][2]; s3 += redc[w][3];
      }
      ws[4 * cb + 0] = s0; ws[4 * cb + 1] = s1;
      ws[4 * cb + 2] = s2; ws[4 * cb + 3] = s3;
    }
  }
}

__global__ void finalize_kernel(const float* __restrict__ ws, float* __restrict__ out) {
  const int lane = threadIdx.x;   // 64 threads, deterministic fixed-order sums
  float s0 = 0.f, s1 = 0.f, s2 = 0.f, s3 = 0.f;
  for (int i = lane; i < NCOMPB; i += 64) {
    s0 += ws[4 * i + 0]; s1 += ws[4 * i + 1];
    s2 += ws[4 * i + 2]; s3 += ws[4 * i + 3];
  }
#pragma unroll
  for (int off = 32; off > 0; off >>= 1) {
    s0 += __shfl_xor(s0, off); s1 += __shfl_xor(s1, off);
    s2 += __shfl_xor(s2, off); s3 += __shfl_xor(s3, off);
  }
  if (lane == 0) {
    const float invB = 1.0f / (float)Bn;
    const float nl_lp  = -0.5f * (s0 * invB) - (s1 * invB);
    const float obj_lp = -0.5f * (s2 * invB) - (s3 * invB);
    out[O_SCALAR] = nl_lp + obj_lp;
  }
}

}  // namespace

extern "C" void kernel_launch(void* const* d_in, const int* in_sizes, int n_in,
                              void* d_out, int out_size, void* d_ws, size_t ws_size,
                              hipStream_t stream) {
  const float* sensory       = (const float*)d_in[0];
  const float* last_location = (const float*)d_in[1];
  const float* action        = (const float*)d_in[2];
  const float* heading       = (const float*)d_in[3];
  const float* mem_locations = (const float*)d_in[4];
  const float* mem_sensory   = (const float*)d_in[5];
  const float* W1 = (const float*)d_in[6];
  const float* b1 = (const float*)d_in[7];
  const float* W2 = (const float*)d_in[8];
  const float* b2 = (const float*)d_in[9];
  const float* V1 = (const float*)d_in[10];
  const float* c1 = (const float*)d_in[11];
  const float* V2 = (const float*)d_in[12];
  const float* c2 = (const float*)d_in[13];
  const float* vs = (const float*)d_in[14];
  const int* mvc  = (const int*)d_in[15];
  const int* wp   = (const int*)d_in[16];
  float* out = (float*)d_out;
  float* ws  = (float*)d_ws;

  fused_kernel<<<dim3(NCOMPB + NCOPY), dim3(256), 0, stream>>>(
      sensory, last_location, action, heading, mem_locations, mem_sensory,
      W1, b1, W2, b2, V1, c1, V2, c2, vs, mvc, wp, out, ws);
  finalize_kernel<<<dim3(1), dim3(64), 0, stream>>>(ws, out);
}

// Round 10
// 30.209 us; speedup vs baseline: 1.6644x; 1.1048x over previous
//
#include <hip/hip_runtime.h>
#include <stdint.h>

namespace {

constexpr int Bn = 2048;
constexpr int Kn = 16;
constexpr int Mn = 131072;             // 2^17

// f32 element offsets in d_out (outputs concatenated flat in return order)
constexpr int O_NEXT   = 0;            // next_location [2048,2]
constexpr int O_SCALAR = Bn * 2;       // 4096 (scalar lp)
constexpr int O_LOC    = O_SCALAR + 1; // 4097
constexpr int O_SENS   = O_LOC + Mn * 2;  // 266241

constexpr int NCOMPB = 512;            // compute blocks FIRST (4 waves/blk, 1 row/wave)
constexpr int NCOPY  = 2048;           // copy blocks

constexpr int SENS_N = Mn * 128;       // 16777216 = 2^24 sens elements
constexpr uint32_t RMASK = Mn - 1;
// INPUT-aligned groups: g covers e = 4g..4g+3. 128%4==0 -> a group never
// crosses a mem-row boundary, so the scatter-window fixup is a pointer select.
constexpr int NGI  = SENS_N / 4;       // 4194304 groups, exact coverage, no edges
constexpr int TOTU = NGI + Mn;         // + loc rows

typedef float f32x4   __attribute__((ext_vector_type(4)));
typedef float f32x4_u __attribute__((ext_vector_type(4), aligned(4)));  // dword-aligned 16B

// ---------------- threefry2x32 (JAX, 20 rounds) ----------------
__device__ __forceinline__ uint32_t rotl32(uint32_t v, int d) {
  return (v << d) | (v >> (32 - d));
}
__device__ __forceinline__ void tfround(uint32_t& x0, uint32_t& x1, int r) {
  x0 += x1; x1 = rotl32(x1, r); x1 ^= x0;
}
__device__ __forceinline__ void threefry2x32(uint32_t k0, uint32_t k1,
                                             uint32_t c0, uint32_t c1,
                                             uint32_t& o0, uint32_t& o1) {
  const uint32_t ks2 = k0 ^ k1 ^ 0x1BD11BDAu;
  uint32_t x0 = c0 + k0, x1 = c1 + k1;
  tfround(x0, x1, 13); tfround(x0, x1, 15); tfround(x0, x1, 26); tfround(x0, x1, 6);
  x0 += k1;  x1 += ks2 + 1u;
  tfround(x0, x1, 17); tfround(x0, x1, 29); tfround(x0, x1, 16); tfround(x0, x1, 24);
  x0 += ks2; x1 += k0 + 2u;
  tfround(x0, x1, 13); tfround(x0, x1, 15); tfround(x0, x1, 26); tfround(x0, x1, 6);
  x0 += k0;  x1 += k1 + 3u;
  tfround(x0, x1, 17); tfround(x0, x1, 29); tfround(x0, x1, 16); tfround(x0, x1, 24);
  x0 += k1;  x1 += ks2 + 4u;
  tfround(x0, x1, 13); tfround(x0, x1, 15); tfround(x0, x1, 26); tfround(x0, x1, 6);
  o0 = x0 + ks2;
  o1 = x1 + k0 + 5u;
}

// XLA ErfInv32 (Giles polynomial)
__device__ __forceinline__ float erfinv_xla(float x) {
  float w = -log1pf(-x * x);
  float p;
  if (w < 5.0f) {
    w -= 2.5f;
    p = 2.81022636e-08f;
    p = fmaf(p, w, 3.43273939e-07f);
    p = fmaf(p, w, -3.5233877e-06f);
    p = fmaf(p, w, -4.39150654e-06f);
    p = fmaf(p, w, 0.00021858087f);
    p = fmaf(p, w, -0.00125372503f);
    p = fmaf(p, w, -0.00417768164f);
    p = fmaf(p, w, 0.246640727f);
    p = fmaf(p, w, 1.50140941f);
  } else {
    w = sqrtf(w) - 3.0f;
    p = -0.000200214257f;
    p = fmaf(p, w, 0.000100950558f);
    p = fmaf(p, w, 0.00134934322f);
    p = fmaf(p, w, -0.00367342844f);
    p = fmaf(p, w, 0.00573950773f);
    p = fmaf(p, w, -0.0076224613f);
    p = fmaf(p, w, 0.00943887047f);
    p = fmaf(p, w, 1.00167406f);
    p = fmaf(p, w, 2.83297682f);
  }
  return p * x;
}
__device__ __forceinline__ float bits_to_normal(uint32_t bits) {
  const float lo = __int_as_float(0xBF7FFFFF);        // nextafter(-1,0) f32
  float f = __uint_as_float((bits >> 9) | 0x3F800000u) - 1.0f;
  float u = fmaxf(lo, f * 2.0f + lo);                 // (hi-lo) rounds to 2.0f
  return 1.41421356237f * erfinv_xla(u);
}
// partitionable threefry: element i <- counter (0, i), output = bits1 ^ bits2
__device__ __forceinline__ float noise_part(uint32_t key_lo, uint32_t i) {
  uint32_t o0, o1;
  threefry2x32(0u, key_lo, 0u, i, o0, o1);
  return bits_to_normal(o0 ^ o1);
}

__device__ __forceinline__ float wave_sum(float v) {
#pragma unroll
  for (int off = 32; off > 0; off >>= 1) v += __shfl_xor(v, off);
  return v;
}

// Wave-parallel localizer: lane owns hidden units 4*lane..4*lane+3.
__device__ __forceinline__ void localizer_wave(
    int lane,
    float x0, float x1, float x2, float x3, float x4, float x5,
    const float* __restrict__ W1, const float* __restrict__ b1,
    const float* __restrict__ W2, const float* __restrict__ b2,
    const float* __restrict__ V1, const float* __restrict__ c1,
    const float* __restrict__ V2, const float* __restrict__ c2,
    float vs_exp,
    float& m0, float& m1, float& sd0, float& sd1) {
  const int h = lane << 2;
  const float4 bb = *(const float4*)(b1 + h);
  const float4 w0 = *(const float4*)(W1 + h);
  const float4 w1 = *(const float4*)(W1 + 256 + h);
  const float4 w2 = *(const float4*)(W1 + 512 + h);
  const float4 w3 = *(const float4*)(W1 + 768 + h);
  const float4 w4 = *(const float4*)(W1 + 1024 + h);
  const float4 w5 = *(const float4*)(W1 + 1280 + h);
  float t0 = bb.x, t1 = bb.y, t2 = bb.z, t3 = bb.w;
  t0 = fmaf(x0, w0.x, t0); t1 = fmaf(x0, w0.y, t1); t2 = fmaf(x0, w0.z, t2); t3 = fmaf(x0, w0.w, t3);
  t0 = fmaf(x1, w1.x, t0); t1 = fmaf(x1, w1.y, t1); t2 = fmaf(x1, w1.z, t2); t3 = fmaf(x1, w1.w, t3);
  t0 = fmaf(x2, w2.x, t0); t1 = fmaf(x2, w2.y, t1); t2 = fmaf(x2, w2.z, t2); t3 = fmaf(x2, w2.w, t3);
  t0 = fmaf(x3, w3.x, t0); t1 = fmaf(x3, w3.y, t1); t2 = fmaf(x3, w3.z, t2); t3 = fmaf(x3, w3.w, t3);
  t0 = fmaf(x4, w4.x, t0); t1 = fmaf(x4, w4.y, t1); t2 = fmaf(x4, w4.z, t2); t3 = fmaf(x4, w4.w, t3);
  t0 = fmaf(x5, w5.x, t0); t1 = fmaf(x5, w5.y, t1); t2 = fmaf(x5, w5.z, t2); t3 = fmaf(x5, w5.w, t3);
  t0 = fmaxf(t0, 0.f); t1 = fmaxf(t1, 0.f); t2 = fmaxf(t2, 0.f); t3 = fmaxf(t3, 0.f);
  const float4 u0 = *(const float4*)(W2 + 2 * h);
  const float4 u1 = *(const float4*)(W2 + 2 * h + 4);
  float pa0 = t0 * u0.x; float pa1 = t0 * u0.y;
  pa0 = fmaf(t1, u0.z, pa0); pa1 = fmaf(t1, u0.w, pa1);
  pa0 = fmaf(t2, u1.x, pa0); pa1 = fmaf(t2, u1.y, pa1);
  pa0 = fmaf(t3, u1.z, pa0); pa1 = fmaf(t3, u1.w, pa1);
  m0 = wave_sum(pa0) + b2[0];
  m1 = wave_sum(pa1) + b2[1];

  const float4 cc = *(const float4*)(c1 + h);
  const float4 v0 = *(const float4*)(V1 + h);
  const float4 v1 = *(const float4*)(V1 + 256 + h);
  float s0 = cc.x, s1 = cc.y, s2 = cc.z, s3 = cc.w;
  s0 = fmaf(m0, v0.x, s0); s1 = fmaf(m0, v0.y, s1); s2 = fmaf(m0, v0.z, s2); s3 = fmaf(m0, v0.w, s3);
  s0 = fmaf(m1, v1.x, s0); s1 = fmaf(m1, v1.y, s1); s2 = fmaf(m1, v1.z, s2); s3 = fmaf(m1, v1.w, s3);
  s0 = fmaxf(s0, 0.f); s1 = fmaxf(s1, 0.f); s2 = fmaxf(s2, 0.f); s3 = fmaxf(s3, 0.f);
  const float4 q0 = *(const float4*)(V2 + 2 * h);
  const float4 q1 = *(const float4*)(V2 + 2 * h + 4);
  float ps0 = s0 * q0.x; float ps1 = s0 * q0.y;
  ps0 = fmaf(s1, q0.z, ps0); ps1 = fmaf(s1, q0.w, ps1);
  ps0 = fmaf(s2, q1.x, ps0); ps1 = fmaf(s2, q1.y, ps1);
  ps0 = fmaf(s3, q1.z, ps0); ps1 = fmaf(s3, q1.w, ps1);
  const float sv0 = wave_sum(ps0) + c2[0];
  const float sv1 = wave_sum(ps1) + c2[1];
  sd0 = fmaf(vs_exp, expf(sv0), 1e-6f);
  sd1 = fmaf(vs_exp, expf(sv1), 1e-6f);
}

__global__ __launch_bounds__(256) void fused_kernel(
    const float* __restrict__ sensory, const float* __restrict__ last_location,
    const float* __restrict__ action, const float* __restrict__ heading,
    const float* __restrict__ mem_locations, const float* __restrict__ mem_sensory,
    const float* __restrict__ W1, const float* __restrict__ b1,
    const float* __restrict__ W2, const float* __restrict__ b2,
    const float* __restrict__ V1, const float* __restrict__ c1,
    const float* __restrict__ V2, const float* __restrict__ c2,
    const float* __restrict__ vs_logits,
    const int* __restrict__ mvc_p, const int* __restrict__ wp_p,
    float* __restrict__ out, float* __restrict__ ws) {
  const int mvc = *mvc_p;
  const uint32_t wpm = (uint32_t)(*wp_p) & RMASK;   // write_ptr mod 2^17

  if (blockIdx.x >= NCOMPB) {
    // -------- streaming copy path: input-aligned groups, pointer-select ----
    // group g covers e = 4g..4g+3 (single mem-row). Source is sensory row
    // (bb<Bn) or mem_sensory — ONE aligned 16B load from the selected base.
    // Store to out+O_SENS+4g is dword-aligned 16B (HW handles, nt bypass).
    const int stride = NCOPY * 256;
    for (int u = (int)(blockIdx.x - NCOMPB) * 256 + (int)threadIdx.x;
         u < TOTU; u += stride) {
      if (u < NGI) {
        const uint32_t r  = (uint32_t)u >> 5;          // mem row (32 groups/row)
        const uint32_t bb = (r - wpm) & RMASK;
        const int e = 4 * u;
        const float* src = (bb < Bn) ? (sensory + ((bb << 7) | (e & 127)))
                                     : (mem_sensory + e);
        const f32x4 q = *(const f32x4*)src;            // 16B-aligned load
        __builtin_nontemporal_store(q, (f32x4_u*)(out + O_SENS + e));
      } else {
        const uint32_t r = (uint32_t)(u - NGI);
        const uint32_t bb = (r - wpm) & RMASK;
        if (bb >= Bn) {
          const float2 v = *(const float2*)(mem_locations + 2 * r);
          out[O_LOC + 2 * r]     = v.x;
          out[O_LOC + 2 * r + 1] = v.y;
        }
      }
    }
  } else {
    // ---------------- compute path: 1 row per wave (blocks 0..511 first) ----
    __shared__ float redc[4][4];
    const int cb = blockIdx.x;
    const int wid = threadIdx.x >> 6;
    const int lane = threadIdx.x & 63;
    const int b = cb * 4 + wid;                   // row 0..2047

    // noise: 4 values lane-split then broadcast
    const uint32_t nk = 1u + ((lane >> 1) & 1u);  // lanes {0,1}->key1, {2,3}->key2
    const uint32_t ni = (uint32_t)(2 * b) + (lane & 1u);
    const float nv = noise_part(nk, ni);
    const float n1a = __shfl(nv, 0);
    const float n1b = __shfl(nv, 1);
    const float n2a = __shfl(nv, 2);
    const float n2b = __shfl(nv, 3);

    const float vs_exp = expf(vs_logits[0]);
    const float l0 = last_location[2 * b], l1 = last_location[2 * b + 1];
    const float a0 = action[4 * b],     a1 = action[4 * b + 1];
    const float a2 = action[4 * b + 2], a3 = action[4 * b + 3];
    const float h0 = heading[4 * b],     h1 = heading[4 * b + 1];
    const float h2 = heading[4 * b + 2], h3 = heading[4 * b + 3];

    // stage 1
    float m10, m11, sd10, sd11;
    localizer_wave(lane, l0, l1, a0, a1, a2, a3, W1, b1, W2, b2, V1, c1, V2, c2,
                   vs_exp, m10, m11, sd10, sd11);
    const float nl0 = m10 + n1a * sd10;
    const float nl1 = m11 + n1b * sd11;
    if (lane == 0) *(float2*)(out + 2 * b) = make_float2(nl0, nl1);

    const float d0 = (nl0 - m10) / sd10;
    const float d1 = (nl1 - m11) / sd11;
    const float v_sq1 = d0 * d0 + d1 * d1;
    const float v_lg1 = logf(sd10) + logf(sd11);

    // stage 2
    float m20, m21, sd20, sd21;
    localizer_wave(lane, nl0, nl1, h0, h1, h2, h3, W1, b1, W2, b2, V1, c1, V2, c2,
                   vs_exp, m20, m21, sd20, sd21);

    // select_location: inverted mask keeps matches at k >= found;
    // guess k = mem_locations[k] (stable top_k over all-(-inf) invalid tail)
    const int found = (mvc < Kn) ? mvc : Kn;
    const bool ignore = (found == 0);
    const float NEG_INF = -__builtin_huge_valf();

    const float qn = sqrtf(m20 * m20 + m21 * m21);
    const float q0 = m20 / qn, q1 = m21 / qn;

    float mk[Kn];
#pragma unroll
    for (int k = 0; k < Kn; ++k) {
      if (k >= found) {
        const float g0 = mem_locations[2 * k], g1 = mem_locations[2 * k + 1];
        const float gn = sqrtf(g0 * g0 + g1 * g1);
        mk[k] = (g0 / gn) * q0 + (g1 / gn) * q1;
      } else {
        mk[k] = NEG_INF;
      }
    }
    float mmax = NEG_INF;
#pragma unroll
    for (int k = 0; k < Kn; ++k) mmax = fmaxf(mmax, mk[k]);
    float wsum = 0.f;
#pragma unroll
    for (int k = 0; k < Kn; ++k) {
      mk[k] = expf(mk[k] - mmax);   // exp(-inf - finite) = 0
      wsum += mk[k];
    }
    float i0 = 0.f, i1 = 0.f;
#pragma unroll
    for (int k = 0; k < Kn; ++k) {
      const float wn = mk[k] / wsum;
      i0 = fmaf(wn, mem_locations[2 * k], i0);
      i1 = fmaf(wn, mem_locations[2 * k + 1], i1);
    }

    const float z0 = (i0 - m20) / sd20, z1 = (i1 - m21) / sd21;
    const float hz0 = -0.5f * z0, hz1 = -0.5f * z1;
    const bool too_far = sqrtf(hz0 * hz0 + hz1 * hz1) > 2.0f;  // NaN -> false
    const float e0 = m20 + n2a * sd20;
    const float e1 = m21 + n2b * sd21;
    const bool c0 = too_far || ignore || __builtin_isnan(i0);
    const bool c1 = too_far || ignore || __builtin_isnan(i1);
    const float o0 = c0 ? i0 : e0;
    const float o1 = c1 ? i1 : e1;

    if (lane == 0) {
      const uint32_t row = (wpm + (uint32_t)b) & RMASK;
      out[O_LOC + 2 * row]     = o0;
      out[O_LOC + 2 * row + 1] = o1;
    }

    const float zo0 = (o0 - m20) / sd20, zo1 = (o1 - m21) / sd21;
    const float v_sq2 = zo0 * zo0 + zo1 * zo1;
    const float v_lg2 = logf(sd20) + logf(sd21);

    if (lane == 0) {
      redc[wid][0] = v_sq1; redc[wid][1] = v_lg1;
      redc[wid][2] = v_sq2; redc[wid][3] = v_lg2;
    }
    __syncthreads();
    if (threadIdx.x == 0) {
      float s0 = 0.f, s1 = 0.f, s2 = 0.f, s3 = 0.f;
#pragma unroll
      for (int w = 0; w < 4; ++w) {
        s0 += redc[w][0]; s1 += redc[w][1]; s2 += redc[w][2]; s3 += redc[w][3];
      }
      ws[4 * cb + 0] = s0; ws[4 * cb + 1] = s1;
      ws[4 * cb + 2] = s2; ws[4 * cb + 3] = s3;
    }
  }
}

__global__ void finalize_kernel(const float* __restrict__ ws, float* __restrict__ out) {
  const int lane = threadIdx.x;   // 64 threads, deterministic fixed-order sums
  float s0 = 0.f, s1 = 0.f, s2 = 0.f, s3 = 0.f;
  for (int i = lane; i < NCOMPB; i += 64) {
    s0 += ws[4 * i + 0]; s1 += ws[4 * i + 1];
    s2 += ws[4 * i + 2]; s3 += ws[4 * i + 3];
  }
#pragma unroll
  for (int off = 32; off > 0; off >>= 1) {
    s0 += __shfl_xor(s0, off); s1 += __shfl_xor(s1, off);
    s2 += __shfl_xor(s2, off); s3 += __shfl_xor(s3, off);
  }
  if (lane == 0) {
    const float invB = 1.0f / (float)Bn;
    const float nl_lp  = -0.5f * (s0 * invB) - (s1 * invB);
    const float obj_lp = -0.5f * (s2 * invB) - (s3 * invB);
    out[O_SCALAR] = nl_lp + obj_lp;
  }
}

}  // namespace

extern "C" void kernel_launch(void* const* d_in, const int* in_sizes, int n_in,
                              void* d_out, int out_size, void* d_ws, size_t ws_size,
                              hipStream_t stream) {
  const float* sensory       = (const float*)d_in[0];
  const float* last_location = (const float*)d_in[1];
  const float* action        = (const float*)d_in[2];
  const float* heading       = (const float*)d_in[3];
  const float* mem_locations = (const float*)d_in[4];
  const float* mem_sensory   = (const float*)d_in[5];
  const float* W1 = (const float*)d_in[6];
  const float* b1 = (const float*)d_in[7];
  const float* W2 = (const float*)d_in[8];
  const float* b2 = (const float*)d_in[9];
  const float* V1 = (const float*)d_in[10];
  const float* c1 = (const float*)d_in[11];
  const float* V2 = (const float*)d_in[12];
  const float* c2 = (const float*)d_in[13];
  const float* vs = (const float*)d_in[14];
  const int* mvc  = (const int*)d_in[15];
  const int* wp   = (const int*)d_in[16];
  float* out = (float*)d_out;
  float* ws  = (float*)d_ws;

  fused_kernel<<<dim3(NCOMPB + NCOPY), dim3(256), 0, stream>>>(
      sensory, last_location, action, heading, mem_locations, mem_sensory,
      W1, b1, W2, b2, V1, c1, V2, c2, vs, mvc, wp, out, ws);
  finalize_kernel<<<dim3(1), dim3(64), 0, stream>>>(ws, out);
}